// Round 1
// 941.945 us; speedup vs baseline: 1.0098x; 1.0098x over previous
//
#include <hip/hip_runtime.h>

// Problem constants
#define B 16
#define LP 128
#define LM 256
#define V 32000
#define E 512
#define H 512
#define DENC 1024          // 2*H
#define K1 2560            // E + 2*DENC
#define G4 2048            // 4*H
#define KIN1 3072          // K1 + H (LSTM1 total K)

// d_out offsets (floats), concat order: logits, p_w, m_w, ctx_new, h1,c1,...,h4,c4
#define OFF_LOGITS 0
#define OFF_PW 512000
#define OFF_MW 514048
#define OFF_CTX 518144
#define OFF_H1 550912
#define OFF_C1 559104
#define OFF_H2 567296
#define OFF_C2 575488
#define OFF_H3 583680
#define OFF_C3 591872
#define OFF_H4 600064
#define OFF_C4 608256

#define ZSPLIT 32          // k-chunks for LSTM z GEMM
#define LSPLIT 8           // k-chunks for logits GEMM
#define LCHUNK (K1 / LSPLIT)   // 320

// ws offsets (floats)
#define WS_ZPART 0                       // ZSPLIT*B*G4 = 1048576
#define WS_D2P   1048576                 // B*H
#define WS_D2M   1056768                 // B*H
#define WS_SP    1064960                 // B*LP
#define WS_SM    1067008                 // B*LM
#define WS_LPART 1071104                 // LSPLIT*B*V = 4096000
// total = 5167104 floats ~= 20.7 MB

__device__ __forceinline__ float sigm(float x) { return 1.0f / (1.0f + expf(-x)); }

// ---------------- LSTM1 z partials, embedding gather fused into LDS staging ----------------
// in = concat(ctx[b][2048], emb[word[b]][512], h1o[b][512]); W = concat(Wx (k<K1), Wh)
__global__ __launch_bounds__(256) void k_lstm_zp1(
    const int* __restrict__ word, const float* __restrict__ ctx,
    const float* __restrict__ emb, const float* __restrict__ h1o,
    const float* __restrict__ Wx, const float* __restrict__ Wh,
    float* __restrict__ zpart)
{
    int j = blockIdx.x * 256 + threadIdx.x;        // [0, 2048)
    const int chunk = KIN1 / ZSPLIT;               // 96
    int k0 = blockIdx.y * chunk;

    __shared__ float xs[96 * 16];                  // [k - k0][b]
    __shared__ int wd[16];
    if (threadIdx.x < 16) wd[threadIdx.x] = word[threadIdx.x];
    __syncthreads();
    for (int idx = threadIdx.x; idx < chunk * 16; idx += 256) {
        int kk = idx >> 4, bb = idx & 15;
        int k = k0 + kk;
        float v;
        if (k < 2 * DENC)      v = ctx[bb * 2 * DENC + k];
        else if (k < K1)       v = emb[(size_t)wd[bb] * E + (k - 2 * DENC)];
        else                   v = h1o[bb * H + (k - K1)];
        xs[idx] = v;
    }
    __syncthreads();

    float acc[16];
    #pragma unroll
    for (int bb = 0; bb < 16; ++bb) acc[bb] = 0.f;

    #pragma unroll 4
    for (int k = k0; k < k0 + chunk; ++k) {
        float w = (k < K1) ? Wx[(size_t)k * G4 + j] : Wh[(size_t)(k - K1) * G4 + j];
        const float4* xp = (const float4*)&xs[(k - k0) * 16];
        float4 x0 = xp[0], x1 = xp[1], x2 = xp[2], x3 = xp[3];
        acc[0]  += x0.x * w; acc[1]  += x0.y * w; acc[2]  += x0.z * w; acc[3]  += x0.w * w;
        acc[4]  += x1.x * w; acc[5]  += x1.y * w; acc[6]  += x1.z * w; acc[7]  += x1.w * w;
        acc[8]  += x2.x * w; acc[9]  += x2.y * w; acc[10] += x2.z * w; acc[11] += x2.w * w;
        acc[12] += x3.x * w; acc[13] += x3.y * w; acc[14] += x3.z * w; acc[15] += x3.w * w;
    }

    float* zp = zpart + (size_t)blockIdx.y * B * G4;
    #pragma unroll
    for (int bb = 0; bb < 16; ++bb) zp[bb * G4 + j] = acc[bb];
}

// ---------------- generic z partials for layers 2-4 (x = prev h, kx = H) ----------------
__global__ __launch_bounds__(256) void k_lstm_zp(
    const float* __restrict__ x, int kx,
    const float* __restrict__ h,
    const float* __restrict__ Wx, const float* __restrict__ Wh,
    float* __restrict__ zpart)
{
    int j = blockIdx.x * 256 + threadIdx.x;
    int K = kx + H;
    int chunk = K / ZSPLIT;                        // 32 for L2-4
    int k0 = blockIdx.y * chunk;
    int k1 = k0 + chunk;

    __shared__ float xs[96 * 16];
    for (int idx = threadIdx.x; idx < chunk * 16; idx += 256) {
        int kk = idx >> 4, bb = idx & 15;
        int k = k0 + kk;
        xs[idx] = (k < kx) ? x[bb * kx + k] : h[bb * H + (k - kx)];
    }
    __syncthreads();

    float acc[16];
    #pragma unroll
    for (int bb = 0; bb < 16; ++bb) acc[bb] = 0.f;

    #pragma unroll 4
    for (int k = k0; k < k1; ++k) {
        float w = (k < kx) ? Wx[(size_t)k * G4 + j] : Wh[(size_t)(k - kx) * G4 + j];
        const float4* xp = (const float4*)&xs[(k - k0) * 16];
        float4 x0 = xp[0], x1 = xp[1], x2 = xp[2], x3 = xp[3];
        acc[0]  += x0.x * w; acc[1]  += x0.y * w; acc[2]  += x0.z * w; acc[3]  += x0.w * w;
        acc[4]  += x1.x * w; acc[5]  += x1.y * w; acc[6]  += x1.z * w; acc[7]  += x1.w * w;
        acc[8]  += x2.x * w; acc[9]  += x2.y * w; acc[10] += x2.z * w; acc[11] += x2.w * w;
        acc[12] += x3.x * w; acc[13] += x3.y * w; acc[14] += x3.z * w; acc[15] += x3.w * w;
    }

    float* zp = zpart + (size_t)blockIdx.y * B * G4;
    #pragma unroll
    for (int bb = 0; bb < 16; ++bb) zp[bb * G4 + j] = acc[bb];
}

// ---------------- gates: reduce partials + bias, apply LSTM nonlinearity ----------------
__global__ __launch_bounds__(256) void k_gates(
    const float* __restrict__ zpart, const float* __restrict__ bias,
    const float* __restrict__ c_old,
    float* __restrict__ h_new, float* __restrict__ c_new)
{
    int b = blockIdx.y;
    int j = blockIdx.x * 256 + threadIdx.x;        // [0, 512)
    float zi = bias[j], zf = bias[H + j], zg = bias[2 * H + j], zo = bias[3 * H + j];
    #pragma unroll
    for (int s = 0; s < ZSPLIT; ++s) {
        const float* zp = zpart + ((size_t)s * B + b) * G4;
        zi += zp[j]; zf += zp[H + j]; zg += zp[2 * H + j]; zo += zp[3 * H + j];
    }
    float c = sigm(zf) * c_old[b * H + j] + sigm(zi) * tanhf(zg);
    float hh = sigm(zo) * tanhf(c);
    c_new[b * H + j] = c;
    h_new[b * H + j] = hh;
}

// ---------------- d2 = h4@W2 + W2b  (both attentions) ----------------
__global__ __launch_bounds__(256) void k_decproj(
    const float* __restrict__ h4,
    const float* __restrict__ pW2w, const float* __restrict__ pW2b,
    const float* __restrict__ mW2w, const float* __restrict__ mW2b,
    float* __restrict__ d2p, float* __restrict__ d2m)
{
    int b = blockIdx.y;
    int j = blockIdx.x * 256 + threadIdx.x;        // [0, 512)
    int which = blockIdx.z;
    const float* W = which ? mW2w : pW2w;
    const float* bb = which ? mW2b : pW2b;
    float* o = which ? d2m : d2p;
    const float* hr = h4 + b * H;
    float acc = bb[j];
    #pragma unroll 8
    for (int k = 0; k < H; ++k) acc += hr[k] * W[k * H + j];
    o[b * H + j] = acc;
}

// ---------------- attention scores: s[b,l] = tanh(enc@W1 + W1b + d2)·V + Vb ----------------
#define TL 16
#define CH 128
__global__ __launch_bounds__(256) void k_attscore(
    const float* __restrict__ encP, const float* __restrict__ encM,
    const float* __restrict__ pW1w, const float* __restrict__ pW1b,
    const float* __restrict__ pVw,  const float* __restrict__ pVb,
    const float* __restrict__ mW1w, const float* __restrict__ mW1b,
    const float* __restrict__ mVw,  const float* __restrict__ mVb,
    const float* __restrict__ d2p,  const float* __restrict__ d2m,
    float* __restrict__ sp, float* __restrict__ sm)
{
    __shared__ float smem[4352];                    // enc tile: CH*20=2560; scores: 256*17=4352
    __shared__ float red2[256];
    int tile = blockIdx.x, b = blockIdx.y, tid = threadIdx.x;
    const int PT = LP / TL;                         // 8 persona tiles
    const float *enc, *W1, *W1bv, *Vw, *Vbv, *d2;
    float* sout; int L, l0;
    if (tile < PT) { enc = encP; W1 = pW1w; W1bv = pW1b; Vw = pVw; Vbv = pVb; d2 = d2p; sout = sp; L = LP; l0 = tile * TL; }
    else           { enc = encM; W1 = mW1w; W1bv = mW1b; Vw = mVw; Vbv = mVb; d2 = d2m; sout = sm; L = LM; l0 = (tile - PT) * TL; }

    float accA[TL], accB[TL];
    #pragma unroll
    for (int l = 0; l < TL; ++l) { accA[l] = 0.f; accB[l] = 0.f; }

    for (int kk0 = 0; kk0 < DENC; kk0 += CH) {
        __syncthreads();
        for (int idx = tid; idx < CH * TL; idx += 256) {
            int kk = idx & (CH - 1), ll = idx >> 7;
            smem[kk * 20 + ll] = enc[(size_t)(b * L + l0 + ll) * DENC + kk0 + kk];
        }
        __syncthreads();
        #pragma unroll 4
        for (int kk = 0; kk < CH; ++kk) {
            float wa = W1[(size_t)(kk0 + kk) * H + tid];
            float wb = W1[(size_t)(kk0 + kk) * H + 256 + tid];
            float el[TL];
            #pragma unroll
            for (int q = 0; q < TL / 4; ++q) {
                float4 t = *(const float4*)&smem[kk * 20 + q * 4];
                el[q * 4 + 0] = t.x; el[q * 4 + 1] = t.y; el[q * 4 + 2] = t.z; el[q * 4 + 3] = t.w;
            }
            #pragma unroll
            for (int l = 0; l < TL; ++l) { accA[l] += el[l] * wa; accB[l] += el[l] * wb; }
        }
    }

    float vA = Vw[tid], vB = Vw[256 + tid];
    float cA = W1bv[tid] + d2[b * H + tid];
    float cB = W1bv[256 + tid] + d2[b * H + 256 + tid];
    float contrib[TL];
    #pragma unroll
    for (int l = 0; l < TL; ++l)
        contrib[l] = tanhf(accA[l] + cA) * vA + tanhf(accB[l] + cB) * vB;

    __syncthreads();
    #pragma unroll
    for (int l = 0; l < TL; ++l) smem[tid * 17 + l] = contrib[l];
    __syncthreads();
    // two-stage reduction over 256 threads for each of TL scores
    {
        int l = tid >> 4, part = tid & 15;
        float p = 0.f;
        #pragma unroll
        for (int g = 0; g < 16; ++g) p += smem[(part * 16 + g) * 17 + l];
        red2[l * 16 + part] = p;
    }
    __syncthreads();
    if (tid < TL) {
        float s = Vbv[0];
        #pragma unroll
        for (int q = 0; q < 16; ++q) s += red2[tid * 16 + q];
        sout[b * L + l0 + tid] = s;
    }
}

// ---------------- fused softmax + weighted ctx (writes p_w/m_w and ctx_new) ----------------
__global__ __launch_bounds__(256) void k_softctx(
    const float* __restrict__ encP, const float* __restrict__ encM,
    const float* __restrict__ sp, const float* __restrict__ sm,
    float* __restrict__ out)
{
    int b = blockIdx.y, which = blockIdx.z, tid = threadIdx.x;
    const float* enc = which ? encM : encP;
    const float* s = which ? sm : sp;
    int L = which ? LM : LP;

    __shared__ float red[256];
    __shared__ float wsm[256];

    float v = (tid < L) ? s[b * L + tid] : -3.4e38f;
    red[tid] = v;
    __syncthreads();
    for (int off = 128; off > 0; off >>= 1) {
        if (tid < off) red[tid] = fmaxf(red[tid], red[tid + off]);
        __syncthreads();
    }
    float mx = red[0];
    __syncthreads();
    float e = (tid < L) ? expf(v - mx) : 0.f;
    red[tid] = e;
    __syncthreads();
    for (int off = 128; off > 0; off >>= 1) {
        if (tid < off) red[tid] += red[tid + off];
        __syncthreads();
    }
    float w = e / red[0];
    wsm[tid] = w;
    __syncthreads();

    if (blockIdx.x == 0 && tid < L)
        out[(which ? (OFF_MW + b * LM) : (OFF_PW + b * LP)) + tid] = w;

    int d = blockIdx.x * 256 + tid;                // [0, DENC)
    float acc = 0.f;
    #pragma unroll 4
    for (int l = 0; l < L; ++l) acc += wsm[l] * enc[(size_t)(b * L + l) * DENC + d];
    out[OFF_CTX + b * 2 * DENC + which * DENC + d] = acc;
}

// ---------------- logits partials: float4 weights, x staged in LDS from d_out ----------------
// lane handles 4 consecutive v; lpart[s][b][v] = sum_{k in chunk} x[b][k] * ow[k][v]
__global__ __launch_bounds__(256) void k_logits_p(
    const float* __restrict__ out_ro, const float* __restrict__ ow,
    float* __restrict__ lpart)
{
    int k0 = blockIdx.y * LCHUNK;                  // chunk = 320
    __shared__ float xs[LCHUNK * 16];              // 20 KB
    for (int idx = threadIdx.x; idx < LCHUNK * 16; idx += 256) {
        int kk = idx >> 4, bb = idx & 15;
        int k = k0 + kk;
        xs[idx] = (k < H) ? out_ro[OFF_H4 + bb * H + k]
                          : out_ro[OFF_CTX + bb * 2 * DENC + (k - H)];
    }
    __syncthreads();

    int v4 = blockIdx.x * 256 + threadIdx.x;       // float4 group index
    if (v4 >= V / 4) return;                       // safe: no further syncs

    float4 acc[16];
    #pragma unroll
    for (int bb = 0; bb < 16; ++bb) acc[bb] = make_float4(0.f, 0.f, 0.f, 0.f);

    #pragma unroll 4
    for (int k = k0; k < k0 + LCHUNK; ++k) {
        float4 w = *(const float4*)&ow[(size_t)k * V + 4 * v4];
        const float4* xp = (const float4*)&xs[(k - k0) * 16];
        float4 x0 = xp[0], x1 = xp[1], x2 = xp[2], x3 = xp[3];
        float xb[16] = { x0.x, x0.y, x0.z, x0.w, x1.x, x1.y, x1.z, x1.w,
                         x2.x, x2.y, x2.z, x2.w, x3.x, x3.y, x3.z, x3.w };
        #pragma unroll
        for (int bb = 0; bb < 16; ++bb) {
            acc[bb].x += xb[bb] * w.x; acc[bb].y += xb[bb] * w.y;
            acc[bb].z += xb[bb] * w.z; acc[bb].w += xb[bb] * w.w;
        }
    }

    #pragma unroll
    for (int bb = 0; bb < 16; ++bb)
        *(float4*)&lpart[((size_t)blockIdx.y * B + bb) * V + 4 * v4] = acc[bb];
}

// ---------------- logits reduce + bias (float4) ----------------
__global__ __launch_bounds__(256) void k_logits_r(
    const float* __restrict__ lpart, const float* __restrict__ ob,
    float* __restrict__ out)
{
    int v4 = blockIdx.x * 256 + threadIdx.x;
    if (v4 >= V / 4) return;
    int b = blockIdx.y;
    float4 s = *(const float4*)&ob[4 * v4];
    #pragma unroll
    for (int p = 0; p < LSPLIT; ++p) {
        float4 t = *(const float4*)&lpart[((size_t)p * B + b) * V + 4 * v4];
        s.x += t.x; s.y += t.y; s.z += t.z; s.w += t.w;
    }
    *(float4*)&out[(size_t)b * V + 4 * v4] = s;
}

extern "C" void kernel_launch(void* const* d_in, const int* in_sizes, int n_in,
                              void* d_out, int out_size, void* d_ws, size_t ws_size,
                              hipStream_t stream)
{
    const int*   word = (const int*)d_in[0];
    const float* encP = (const float*)d_in[1];
    const float* encM = (const float*)d_in[2];
    const float* ctx  = (const float*)d_in[3];
    const float* h1o  = (const float*)d_in[4];
    const float* c1o  = (const float*)d_in[5];
    const float* h2o  = (const float*)d_in[6];
    const float* c2o  = (const float*)d_in[7];
    const float* h3o  = (const float*)d_in[8];
    const float* c3o  = (const float*)d_in[9];
    const float* h4o  = (const float*)d_in[10];
    const float* c4o  = (const float*)d_in[11];
    const float* emb  = (const float*)d_in[12];
    const float* Wx1 = (const float*)d_in[13]; const float* Wh1 = (const float*)d_in[14]; const float* b1 = (const float*)d_in[15];
    const float* Wx2 = (const float*)d_in[16]; const float* Wh2 = (const float*)d_in[17]; const float* b2 = (const float*)d_in[18];
    const float* Wx3 = (const float*)d_in[19]; const float* Wh3 = (const float*)d_in[20]; const float* b3 = (const float*)d_in[21];
    const float* Wx4 = (const float*)d_in[22]; const float* Wh4 = (const float*)d_in[23]; const float* b4 = (const float*)d_in[24];
    const float* pW1w = (const float*)d_in[25]; const float* pW1b = (const float*)d_in[26];
    const float* pW2w = (const float*)d_in[27]; const float* pW2b = (const float*)d_in[28];
    const float* pVw  = (const float*)d_in[29]; const float* pVb  = (const float*)d_in[30];
    const float* mW1w = (const float*)d_in[31]; const float* mW1b = (const float*)d_in[32];
    const float* mW2w = (const float*)d_in[33]; const float* mW2b = (const float*)d_in[34];
    const float* mVw  = (const float*)d_in[35]; const float* mVb  = (const float*)d_in[36];
    const float* outw = (const float*)d_in[37]; const float* outb = (const float*)d_in[38];

    float* out = (float*)d_out;
    float* ws  = (float*)d_ws;
    float* ZPART = ws + WS_ZPART;
    float* D2P   = ws + WS_D2P;
    float* D2M   = ws + WS_D2M;
    float* SP    = ws + WS_SP;
    float* SM    = ws + WS_SM;
    float* LPART = ws + WS_LPART;

    dim3 blk(256);

    // 1. LSTM chain (embed fused into layer-1 staging; split-K partials + fused reduce/gates)
    k_lstm_zp1<<<dim3(8, ZSPLIT), blk, 0, stream>>>(word, ctx, emb, h1o, Wx1, Wh1, ZPART);
    k_gates   <<<dim3(2, B), blk, 0, stream>>>(ZPART, b1, c1o, out + OFF_H1, out + OFF_C1);

    k_lstm_zp<<<dim3(8, ZSPLIT), blk, 0, stream>>>(out + OFF_H1, H, h2o, Wx2, Wh2, ZPART);
    k_gates  <<<dim3(2, B), blk, 0, stream>>>(ZPART, b2, c2o, out + OFF_H2, out + OFF_C2);

    k_lstm_zp<<<dim3(8, ZSPLIT), blk, 0, stream>>>(out + OFF_H2, H, h3o, Wx3, Wh3, ZPART);
    k_gates  <<<dim3(2, B), blk, 0, stream>>>(ZPART, b3, c3o, out + OFF_H3, out + OFF_C3);

    k_lstm_zp<<<dim3(8, ZSPLIT), blk, 0, stream>>>(out + OFF_H3, H, h4o, Wx4, Wh4, ZPART);
    k_gates  <<<dim3(2, B), blk, 0, stream>>>(ZPART, b4, c4o, out + OFF_H4, out + OFF_C4);

    // 2. attention decoder projections (p and m)
    k_decproj<<<dim3(2, B, 2), blk, 0, stream>>>(out + OFF_H4, pW2w, pW2b, mW2w, mW2b, D2P, D2M);

    // 3. attention scores (persona tiles 0..7, msg tiles 8..23)
    k_attscore<<<dim3(LP / TL + LM / TL, B), blk, 0, stream>>>(
        encP, encM, pW1w, pW1b, pVw, pVb, mW1w, mW1b, mVw, mVb, D2P, D2M, SP, SM);

    // 4. fused softmax + weighted ctx (writes p_w, m_w, ctx_new)
    k_softctx<<<dim3(DENC / 256, B, 2), blk, 0, stream>>>(encP, encM, SP, SM, out);

    // 5. logits = [h4, ctx_new] @ out_w + out_b (split-K float4 partials + reduce)
    k_logits_p<<<dim3((V / 4 + 255) / 256, LSPLIT), blk, 0, stream>>>(out, outw, LPART);
    k_logits_r<<<dim3((V / 4 + 255) / 256, B), blk, 0, stream>>>(LPART, outb, out);
}